// Round 7
// baseline (42.385 us; speedup 1.0000x reference)
//
#include <hip/hip_runtime.h>
#include <math.h>

typedef short bf16x8 __attribute__((ext_vector_type(8)));
typedef float f32x4 __attribute__((ext_vector_type(4)));

__device__ __forceinline__ int cvt2(float lo, float hi) {
    int r;
    asm("v_cvt_pk_bf16_f32 %0, %1, %2" : "=v"(r) : "v"(lo), "v"(hi));
    return r;
}

#define BAR() do {                                                        \
        asm volatile("s_waitcnt lgkmcnt(0)" ::: "memory");                \
        __builtin_amdgcn_s_barrier();                                     \
        __builtin_amdgcn_sched_barrier(0);                                \
    } while (0)

// ---------------------------------------------------------------------------
// Fused gates GEMM + GRU elementwise (round-4 pipeline, unchanged schedule).
// grid 256: blocks 0..127 compute the 6 gate tiles for a 64-row x 16-col
// patch, GRU in-register, write h1' (f32) and res (bf16, RNE — bit-identical
// to stage-time rounding). Blocks 128..255 zero the split-K atomic targets
// and convert w_fc1/w_fc3 to bf16 (w1b/w3b) for the fc kernels.
__global__ __launch_bounds__(256, 2) void gates_k(
    const float* __restrict__ x, const float* __restrict__ h1,
    const float* __restrict__ w_ih, const float* __restrict__ w_hh,
    const float* __restrict__ b_ih, const float* __restrict__ b_hh,
    const float* __restrict__ w_fc1, const float* __restrict__ w_fc3,
    float* __restrict__ h1p, short* __restrict__ resb,
    float* __restrict__ f1p, float* __restrict__ outz,
    short* __restrict__ w1b, short* __restrict__ w3b)
{
    __shared__ short As[2][128 * 64];   // 32 KB
    __shared__ short Ws[2][96 * 64];    // 24 KB
    const int tid  = threadIdx.x;
    const int lane = tid & 63;
    const int wv   = tid >> 6;
    const int b    = blockIdx.x;

    if (b >= 128) {
        // -------- converter / zeroing blocks (necessary work only) --------
        const int w = b - 128;            // 0..127
        f32x4 z = {};
        *(f32x4*)(f1p + w * 1024 + tid * 4) = z;             // zero f1p row w
        if (tid < 64) *(f32x4*)(outz + w * 256 + tid * 4) = z; // zero out row w
        {   // w_fc1 -> bf16 (8192 elems per block)
            const float* s = w_fc1 + w * 8192 + tid * 32;
            short*       d = w1b   + w * 8192 + tid * 32;
            #pragma unroll
            for (int i = 0; i < 4; ++i) {
                f32x4 v0 = *(const f32x4*)(s + i * 8);
                f32x4 v1 = *(const f32x4*)(s + i * 8 + 4);
                int4 p;
                p.x = cvt2(v0[0], v0[1]); p.y = cvt2(v0[2], v0[3]);
                p.z = cvt2(v1[0], v1[1]); p.w = cvt2(v1[2], v1[3]);
                *(int4*)(d + i * 8) = p;
            }
        }
        {   // w_fc3 -> bf16 (2048 elems per block)
            const float* s = w_fc3 + w * 2048 + tid * 8;
            short*       d = w3b   + w * 2048 + tid * 8;
            f32x4 v0 = *(const f32x4*)s, v1 = *(const f32x4*)(s + 4);
            int4 p;
            p.x = cvt2(v0[0], v0[1]); p.y = cvt2(v0[2], v0[3]);
            p.z = cvt2(v1[0], v1[1]); p.w = cvt2(v1[2], v1[3]);
            *(int4*)d = p;
        }
        return;
    }

    const int tile = b & 63;              // (tile, rg) pair b / b+64 share XCD
    const int rg   = b >> 6;
    const int c0   = tile * 16;
    const int row0 = rg * 64;
    const int r0 = tid >> 3, kc = tid & 7;

    const float* aP[4];
    int saI[4];
    #pragma unroll
    for (int i = 0; i < 4; ++i) {
        int ma = r0 + 32 * i;                         // 0..127
        const float* src = (i < 2) ? x : h1;
        aP[i] = src + (row0 + (ma & 63)) * 1024 + kc * 8;
        saI[i] = (ma * 64 + kc * 8) ^ ((ma & 7) << 3);
    }
    const float* wP[3];
    int swI[3];
    #pragma unroll
    for (int i = 0; i < 3; ++i) {
        int mw = r0 + 32 * i;                         // 0..95
        int g = mw >> 4;                              // gate 0..5
        const float* src = (g < 3) ? w_ih : w_hh;
        wP[i] = src + ((g % 3) * 1024 + c0 + (mw & 15)) * 1024 + kc * 8;
        swI[i] = (mw * 64 + kc * 8) ^ ((mw & 7) << 3);
    }

    f32x4 A[2][4][2], W[2][3][2];
    f32x4 acc[6] = {};

#define G_ISSUE(kt, s) do {                                               \
        _Pragma("unroll")                                                 \
        for (int i = 0; i < 4; ++i) {                                     \
            A[s][i][0] = *(const f32x4*)(aP[i] + (kt) * 64);              \
            A[s][i][1] = *(const f32x4*)(aP[i] + (kt) * 64 + 4);          \
        }                                                                 \
        _Pragma("unroll")                                                 \
        for (int i = 0; i < 3; ++i) {                                     \
            W[s][i][0] = *(const f32x4*)(wP[i] + (kt) * 64);              \
            W[s][i][1] = *(const f32x4*)(wP[i] + (kt) * 64 + 4);          \
        }                                                                 \
    } while (0)

#define G_STAGE(s, bb) do {                                               \
        _Pragma("unroll")                                                 \
        for (int i = 0; i < 4; ++i) {                                     \
            int4 p;                                                       \
            p.x = cvt2(A[s][i][0][0], A[s][i][0][1]);                     \
            p.y = cvt2(A[s][i][0][2], A[s][i][0][3]);                     \
            p.z = cvt2(A[s][i][1][0], A[s][i][1][1]);                     \
            p.w = cvt2(A[s][i][1][2], A[s][i][1][3]);                     \
            *(int4*)&As[bb][saI[i]] = p;                                  \
        }                                                                 \
        _Pragma("unroll")                                                 \
        for (int i = 0; i < 3; ++i) {                                     \
            int4 q;                                                       \
            q.x = cvt2(W[s][i][0][0], W[s][i][0][1]);                     \
            q.y = cvt2(W[s][i][0][2], W[s][i][0][3]);                     \
            q.z = cvt2(W[s][i][1][0], W[s][i][1][1]);                     \
            q.w = cvt2(W[s][i][1][2], W[s][i][1][3]);                     \
            *(int4*)&Ws[bb][swI[i]] = q;                                  \
        }                                                                 \
    } while (0)

#define G_COMPUTE(bb) do {                                                \
        _Pragma("unroll")                                                 \
        for (int kk = 0; kk < 64; kk += 32) {                             \
            const int kw = kk + 8 * (lane >> 4);                          \
            const int ar = wv * 16 + (lane & 15);                         \
            bf16x8 afx = *(const bf16x8*)&As[bb][(ar * 64 + kw) ^ ((ar & 7) << 3)]; \
            bf16x8 afh = *(const bf16x8*)&As[bb][((ar + 64) * 64 + kw) ^ ((ar & 7) << 3)]; \
            _Pragma("unroll")                                             \
            for (int g = 0; g < 6; ++g) {                                 \
                int br = g * 16 + (lane & 15);                            \
                bf16x8 bw = *(const bf16x8*)&Ws[bb][(br * 64 + kw) ^ ((br & 7) << 3)]; \
                acc[g] = __builtin_amdgcn_mfma_f32_16x16x32_bf16(         \
                    (g < 3) ? afx : afh, bw, acc[g], 0, 0, 0);            \
            }                                                             \
        }                                                                 \
    } while (0)

    G_ISSUE(0, 0); G_ISSUE(1, 1);
    #pragma unroll 1
    for (int kt2 = 0; kt2 < 8; ++kt2) {
        const int kt = 2 * kt2;
        G_STAGE(0, 0); if (kt + 2 < 16) G_ISSUE(kt + 2, 0); BAR(); G_COMPUTE(0);
        G_STAGE(1, 1); if (kt + 3 < 16) G_ISSUE(kt + 3, 1); BAR(); G_COMPUTE(1);
    }
#undef G_ISSUE
#undef G_STAGE
#undef G_COMPUTE

    // ---- GRU epilogue (in-register) ----
    const int j = c0 + (lane & 15);
    const float bir = b_ih[j], biz = b_ih[1024 + j], bin = b_ih[2048 + j];
    const float bhr = b_hh[j], bhz = b_hh[1024 + j], bhn = b_hh[2048 + j];
    const int rbase = row0 + wv * 16 + (lane >> 4) * 4;
    #pragma unroll
    for (int r = 0; r < 4; ++r) {
        const int row = rbase + r;
        float ir  = acc[0][r] + bir, iz = acc[1][r] + biz, inn = acc[2][r] + bin;
        float hr  = acc[3][r] + bhr, hz = acc[4][r] + bhz, hn  = acc[5][r] + bhn;
        float rr = 1.0f / (1.0f + __expf(-(ir + hr)));
        float zz = 1.0f / (1.0f + __expf(-(iz + hz)));
        float nn = tanhf(inn + rr * hn);
        float h1v = h1[row * 1024 + j];
        float hp  = (1.0f - zz) * nn + zz * h1v;
        h1p[row * 1024 + j] = hp;
        float rv = hp + x[row * 1024 + j];
        resb[row * 1024 + j] = (short)cvt2(rv, rv);   // bf16 RNE, low half
    }
}

// ---------------------------------------------------------------------------
// Tiled GEMM (fc1 / fc3): out rows [rg*64,+64) cols [c0,+NT)
// += act[128][1024] @ wgt[N][1024]^T ; split-K via ksbits + atomics.
// wgt is ALWAYS bf16 (pre-converted). ABF16: act is bf16 (fc1: res);
// else f32 with optional RELUA at staging (fc3: relu(f1p)).
template<int NT, bool ABF16, bool RELUA>
__global__ __launch_bounds__(256, 2) void gemm_k(
    const void* __restrict__ actv, const short* __restrict__ wgt,
    const float* __restrict__ bias,
    float* __restrict__ out, int ldo, int nkt, int ksbits)
{
    constexpr int CT = NT / 16;
    __shared__ short As[2][64 * 64];
    __shared__ short Ws[2][NT * 64];

    const int tid  = threadIdx.x;
    const int lane = tid & 63;
    const int wv   = tid >> 6;

    const int ks   = blockIdx.x & ((1 << ksbits) - 1);
    const int rest = blockIdx.x >> ksbits;
    const int rg   = rest & 1;
    const int tile = rest >> 1;
    const int c0   = tile * NT;
    const int row0 = rg * 64;
    const int kt0  = ks * nkt;

    const int r0 = tid >> 3, kc = tid & 7;
    const float* aPf = (const float*)actv + (row0 + r0) * 1024 + kt0 * 64 + kc * 8;
    const short* aPb = (const short*)actv + (row0 + r0) * 1024 + kt0 * 64 + kc * 8;
    const short* wP  = wgt + (c0 + r0) * 1024 + kt0 * 64 + kc * 8;
    const bool wAct = (tid < NT * 8);

    const int sa0 = (r0 * 64 + kc * 8) ^ ((r0 & 7) << 3);
    const int sa1 = ((r0 + 32) * 64 + kc * 8) ^ ((r0 & 7) << 3);

    f32x4 Af[4][4];      // f32 A path (fc3)
    int4  Ab[4][2];      // bf16 A path (fc1)
    int4  Wb[4];
    f32x4 acc[CT] = {};

#define ISSUE(kt, s) do {                                                 \
        if constexpr (ABF16) {                                            \
            Ab[s][0] = *(const int4*)(aPb + (kt) * 64);                   \
            Ab[s][1] = *(const int4*)(aPb + (kt) * 64 + 32 * 1024);       \
        } else {                                                          \
            Af[s][0] = *(const f32x4*)(aPf + (kt) * 64);                  \
            Af[s][1] = *(const f32x4*)(aPf + (kt) * 64 + 4);              \
            Af[s][2] = *(const f32x4*)(aPf + (kt) * 64 + 32768);          \
            Af[s][3] = *(const f32x4*)(aPf + (kt) * 64 + 32772);          \
        }                                                                 \
        if (wAct) Wb[s] = *(const int4*)(wP + (kt) * 64);                 \
    } while (0)

#define RL(v) (RELUA ? fmaxf((v), 0.0f) : (v))

#define STAGE(s, b) do {                                                  \
        if constexpr (ABF16) {                                            \
            *(int4*)&As[b][sa0] = Ab[s][0];                               \
            *(int4*)&As[b][sa1] = Ab[s][1];                               \
        } else {                                                          \
            int4 p0, p1;                                                  \
            p0.x = cvt2(RL(Af[s][0][0]), RL(Af[s][0][1]));                \
            p0.y = cvt2(RL(Af[s][0][2]), RL(Af[s][0][3]));                \
            p0.z = cvt2(RL(Af[s][1][0]), RL(Af[s][1][1]));                \
            p0.w = cvt2(RL(Af[s][1][2]), RL(Af[s][1][3]));                \
            p1.x = cvt2(RL(Af[s][2][0]), RL(Af[s][2][1]));                \
            p1.y = cvt2(RL(Af[s][2][2]), RL(Af[s][2][3]));                \
            p1.z = cvt2(RL(Af[s][3][0]), RL(Af[s][3][1]));                \
            p1.w = cvt2(RL(Af[s][3][2]), RL(Af[s][3][3]));                \
            *(int4*)&As[b][sa0] = p0;                                     \
            *(int4*)&As[b][sa1] = p1;                                     \
        }                                                                 \
        if (wAct) *(int4*)&Ws[b][sa0] = Wb[s];                            \
    } while (0)

#define COMPUTE(b) do {                                                   \
        _Pragma("unroll")                                                 \
        for (int kk = 0; kk < 64; kk += 32) {                             \
            const int kw = kk + 8 * (lane >> 4);                          \
            const int ar = wv * 16 + (lane & 15);                         \
            bf16x8 af = *(const bf16x8*)&As[b][(ar * 64 + kw) ^ ((ar & 7) << 3)]; \
            bf16x8 bw[CT];                                                \
            _Pragma("unroll")                                             \
            for (int ct = 0; ct < CT; ++ct) {                             \
                int br = ct * 16 + (lane & 15);                           \
                bw[ct] = *(const bf16x8*)&Ws[b][(br * 64 + kw) ^ ((br & 7) << 3)]; \
            }                                                             \
            _Pragma("unroll")                                             \
            for (int ct = 0; ct < CT; ++ct)                               \
                acc[ct] = __builtin_amdgcn_mfma_f32_16x16x32_bf16(        \
                    af, bw[ct], acc[ct], 0, 0, 0);                        \
        }                                                                 \
    } while (0)

    ISSUE(0, 0); ISSUE(1, 1); ISSUE(2, 2); ISSUE(3, 3);

    #pragma unroll 1
    for (int g = 0; g < nkt / 4; ++g) {
        const int kt = 4 * g;
        STAGE(0, 0); if (kt + 4 < nkt) ISSUE(kt + 4, 0); BAR(); COMPUTE(0);
        STAGE(1, 1); if (kt + 5 < nkt) ISSUE(kt + 5, 1); BAR(); COMPUTE(1);
        STAGE(2, 0); if (kt + 6 < nkt) ISSUE(kt + 6, 2); BAR(); COMPUTE(0);
        STAGE(3, 1); if (kt + 7 < nkt) ISSUE(kt + 7, 3); BAR(); COMPUTE(1);
    }

#undef ISSUE
#undef RL
#undef STAGE
#undef COMPUTE

    #pragma unroll
    for (int ct = 0; ct < CT; ++ct) {
        int col = c0 + ct * 16 + (lane & 15);
        float bv = (bias && ks == 0) ? bias[col] : 0.0f;
        #pragma unroll
        for (int r = 0; r < 4; ++r) {
            int row = row0 + wv * 16 + (lane >> 4) * 4 + r;
            unsafeAtomicAdd(&out[row * ldo + col], acc[ct][r] + bv);
        }
    }
}

extern "C" void kernel_launch(void* const* d_in, const int* in_sizes, int n_in,
                              void* d_out, int out_size, void* d_ws, size_t ws_size,
                              hipStream_t stream)
{
    const float* x     = (const float*)d_in[0];
    const float* h1    = (const float*)d_in[1];
    const float* w_ih  = (const float*)d_in[2];
    const float* w_hh  = (const float*)d_in[3];
    const float* b_ih  = (const float*)d_in[4];
    const float* b_hh  = (const float*)d_in[5];
    const float* w_fc1 = (const float*)d_in[6];
    const float* b_fc1 = (const float*)d_in[7];
    const float* w_fc3 = (const float*)d_in[8];
    const float* b_fc3 = (const float*)d_in[9];

    float* out = (float*)d_out;          // [128][256]
    float* h1p = out + 128 * 256;        // [128][1024]

    char* ws = (char*)d_ws;
    short* resb = (short*)ws;                                // [128][1024] bf16
    float* f1p  = (float*)(ws + 256 * 1024);                 // [128][1024] f32
    short* w1b  = (short*)(ws + 768 * 1024);                 // [1024][1024] bf16
    short* w3b  = (short*)(ws + 768 * 1024 + 2 * 1024 * 1024); // [256][1024] bf16

    // gates GEMM + GRU -> h1p (f32) + resb (bf16); converters zero f1p/out
    // and produce w1b/w3b
    gates_k<<<256, 256, 0, stream>>>(x, h1, w_ih, w_hh, b_ih, b_hh,
                                     w_fc1, w_fc3, h1p, resb, f1p, out,
                                     w1b, w3b);
    // f1p += resb @ w1b^T + b_fc1   (64 tiles x 2 rg x 2 ks = 256 blocks)
    gemm_k<16, true, false><<<256, 256, 0, stream>>>(
        resb, w1b, b_fc1, f1p, 1024, 8, 1);
    // out += relu(f1p) @ w3b^T + b_fc3  (16 x 2 x 2 = 64 blocks)
    gemm_k<16, false, true><<<64, 256, 0, stream>>>(
        f1p, w3b, b_fc3, out, 256, 8, 1);
}

// Round 8
// 32.613 us; speedup vs baseline: 1.2996x; 1.2996x over previous
//
#include <hip/hip_runtime.h>
#include <math.h>

typedef short bf16x8 __attribute__((ext_vector_type(8)));
typedef float f32x4 __attribute__((ext_vector_type(4)));

__device__ __forceinline__ int cvt2(float lo, float hi) {
    int r;
    asm("v_cvt_pk_bf16_f32 %0, %1, %2" : "=v"(r) : "v"(lo), "v"(hi));
    return r;
}

#define BAR() do {                                                        \
        asm volatile("s_waitcnt lgkmcnt(0)" ::: "memory");                \
        __builtin_amdgcn_s_barrier();                                     \
        __builtin_amdgcn_sched_barrier(0);                                \
    } while (0)

// ---------------------------------------------------------------------------
// Fused gates GEMM + GRU elementwise. grid 128 (NO helper blocks — R6/R7
// showed concurrent helper traffic evicts the L2 working set and regresses).
// Block computes all 6 gate tiles (i_r,i_z,i_n,h_r,h_z,h_n) for a 64-row x
// 16-col patch, GRU in-register, writes h1' and res = h1' + x.
// Pipeline (THE one change vs round-4): W prefetched 4-deep (weights are
// L3/HBM, ~500+cy), A 2-deep (x/h1 L2-hot); double-buffered LDS; lgkm-only
// barriers keep globals in flight. launch_bounds(256,1): grid=128 is 1
// block/CU anyway; lets ~220 VGPR allocate without spill.
__global__ __launch_bounds__(256, 1) void gates_k(
    const float* __restrict__ x, const float* __restrict__ h1,
    const float* __restrict__ w_ih, const float* __restrict__ w_hh,
    const float* __restrict__ b_ih, const float* __restrict__ b_hh,
    float* __restrict__ h1p, float* __restrict__ res,
    float* __restrict__ zf1p, float* __restrict__ zout)
{
    __shared__ short As[2][128 * 64];   // 32 KB
    __shared__ short Ws[2][96 * 64];    // 24 KB
    const int tid  = threadIdx.x;
    const int lane = tid & 63;
    const int wv   = tid >> 6;
    const int b    = blockIdx.x;

    // zero split-K atomic targets (fc1 pre-act, fc3 output region)
    {
        int id = b * 256 + tid;                    // 0..32767
        f32x4 z = {};
        *(f32x4*)(zf1p + id * 4) = z;
        zout[id] = 0.0f;
    }

    const int tile = b & 63;              // (tile, rg) pair b / b+64 share XCD
    const int rg   = b >> 6;
    const int c0   = tile * 16;
    const int row0 = rg * 64;
    const int r0 = tid >> 3, kc = tid & 7;

    const float* aP[4];
    int saI[4];
    #pragma unroll
    for (int i = 0; i < 4; ++i) {
        int ma = r0 + 32 * i;                         // 0..127
        const float* src = (i < 2) ? x : h1;
        aP[i] = src + (row0 + (ma & 63)) * 1024 + kc * 8;
        saI[i] = (ma * 64 + kc * 8) ^ ((ma & 7) << 3);
    }
    const float* wP[3];
    int swI[3];
    #pragma unroll
    for (int i = 0; i < 3; ++i) {
        int mw = r0 + 32 * i;                         // 0..95
        int g = mw >> 4;                              // gate 0..5
        const float* src = (g < 3) ? w_ih : w_hh;
        wP[i] = src + ((g % 3) * 1024 + c0 + (mw & 15)) * 1024 + kc * 8;
        swI[i] = (mw * 64 + kc * 8) ^ ((mw & 7) << 3);
    }

    f32x4 A[2][4][2];     // 2-deep A sets
    f32x4 W[4][3][2];     // 4-deep W sets
    f32x4 acc[6] = {};

#define G_ISSUE_A(kt, s) do {                                             \
        _Pragma("unroll")                                                 \
        for (int i = 0; i < 4; ++i) {                                     \
            A[s][i][0] = *(const f32x4*)(aP[i] + (kt) * 64);              \
            A[s][i][1] = *(const f32x4*)(aP[i] + (kt) * 64 + 4);          \
        }                                                                 \
    } while (0)

#define G_ISSUE_W(kt, s) do {                                             \
        _Pragma("unroll")                                                 \
        for (int i = 0; i < 3; ++i) {                                     \
            W[s][i][0] = *(const f32x4*)(wP[i] + (kt) * 64);              \
            W[s][i][1] = *(const f32x4*)(wP[i] + (kt) * 64 + 4);          \
        }                                                                 \
    } while (0)

#define G_STAGE(sa, sw, bb) do {                                          \
        _Pragma("unroll")                                                 \
        for (int i = 0; i < 4; ++i) {                                     \
            int4 p;                                                       \
            p.x = cvt2(A[sa][i][0][0], A[sa][i][0][1]);                   \
            p.y = cvt2(A[sa][i][0][2], A[sa][i][0][3]);                   \
            p.z = cvt2(A[sa][i][1][0], A[sa][i][1][1]);                   \
            p.w = cvt2(A[sa][i][1][2], A[sa][i][1][3]);                   \
            *(int4*)&As[bb][saI[i]] = p;                                  \
        }                                                                 \
        _Pragma("unroll")                                                 \
        for (int i = 0; i < 3; ++i) {                                     \
            int4 q;                                                       \
            q.x = cvt2(W[sw][i][0][0], W[sw][i][0][1]);                   \
            q.y = cvt2(W[sw][i][0][2], W[sw][i][0][3]);                   \
            q.z = cvt2(W[sw][i][1][0], W[sw][i][1][1]);                   \
            q.w = cvt2(W[sw][i][1][2], W[sw][i][1][3]);                   \
            *(int4*)&Ws[bb][swI[i]] = q;                                  \
        }                                                                 \
    } while (0)

#define G_COMPUTE(bb) do {                                                \
        _Pragma("unroll")                                                 \
        for (int kk = 0; kk < 64; kk += 32) {                             \
            const int kw = kk + 8 * (lane >> 4);                          \
            const int ar = wv * 16 + (lane & 15);                         \
            bf16x8 afx = *(const bf16x8*)&As[bb][(ar * 64 + kw) ^ ((ar & 7) << 3)]; \
            bf16x8 afh = *(const bf16x8*)&As[bb][((ar + 64) * 64 + kw) ^ ((ar & 7) << 3)]; \
            _Pragma("unroll")                                             \
            for (int g = 0; g < 6; ++g) {                                 \
                int br = g * 16 + (lane & 15);                            \
                bf16x8 bw = *(const bf16x8*)&Ws[bb][(br * 64 + kw) ^ ((br & 7) << 3)]; \
                acc[g] = __builtin_amdgcn_mfma_f32_16x16x32_bf16(         \
                    (g < 3) ? afx : afh, bw, acc[g], 0, 0, 0);            \
            }                                                             \
        }                                                                 \
    } while (0)

// one K-step: stage current, refill W (4 ahead) and A (2 ahead), sync, mma
#define G_STEP(k, sw, sa, bb) do {                                        \
        G_STAGE(sa, sw, bb);                                              \
        if ((k) + 4 < 16) G_ISSUE_W((k) + 4, sw);                         \
        if ((k) + 2 < 16) G_ISSUE_A((k) + 2, sa);                         \
        BAR();                                                            \
        G_COMPUTE(bb);                                                    \
    } while (0)

    G_ISSUE_W(0, 0); G_ISSUE_W(1, 1); G_ISSUE_W(2, 2); G_ISSUE_W(3, 3);
    G_ISSUE_A(0, 0); G_ISSUE_A(1, 1);

    #pragma unroll 1
    for (int kt0 = 0; kt0 < 16; kt0 += 4) {
        G_STEP(kt0 + 0, 0, 0, 0);
        G_STEP(kt0 + 1, 1, 1, 1);
        G_STEP(kt0 + 2, 2, 0, 0);
        G_STEP(kt0 + 3, 3, 1, 1);
    }

#undef G_ISSUE_A
#undef G_ISSUE_W
#undef G_STAGE
#undef G_COMPUTE
#undef G_STEP

    // ---- GRU epilogue (in-register) ----
    const int j = c0 + (lane & 15);
    const float bir = b_ih[j], biz = b_ih[1024 + j], bin = b_ih[2048 + j];
    const float bhr = b_hh[j], bhz = b_hh[1024 + j], bhn = b_hh[2048 + j];
    const int rbase = row0 + wv * 16 + (lane >> 4) * 4;
    #pragma unroll
    for (int r = 0; r < 4; ++r) {
        const int row = rbase + r;
        float ir  = acc[0][r] + bir, iz = acc[1][r] + biz, inn = acc[2][r] + bin;
        float hr  = acc[3][r] + bhr, hz = acc[4][r] + bhz, hn  = acc[5][r] + bhn;
        float rr = 1.0f / (1.0f + __expf(-(ir + hr)));
        float zz = 1.0f / (1.0f + __expf(-(iz + hz)));
        float nn = tanhf(inn + rr * hn);
        float h1v = h1[row * 1024 + j];
        float hp  = (1.0f - zz) * nn + zz * h1v;
        h1p[row * 1024 + j] = hp;
        res[row * 1024 + j] = hp + x[row * 1024 + j];
    }
}

// ---------------------------------------------------------------------------
// Generic tiled GEMM (fc1 / fc3): out rows [rg*64,+64) cols [c0,+NT)
// (+)= act[128][1024] @ wgt[N][1024]^T ; split-K via ksbits + atomics.
// (byte-for-byte the round-4 version — known good)
template<int NT, bool ATOMIC, bool RELUA>
__global__ __launch_bounds__(256, 2) void gemm_k(
    const float* __restrict__ act, const float* __restrict__ wgt,
    const float* __restrict__ bias,
    float* __restrict__ out, int ldo, int nkt, int ksbits)
{
    constexpr int CT = NT / 16;
    __shared__ short As[2][64 * 64];
    __shared__ short Ws[2][NT * 64];

    const int tid  = threadIdx.x;
    const int lane = tid & 63;
    const int wv   = tid >> 6;

    const int ks   = blockIdx.x & ((1 << ksbits) - 1);
    const int rest = blockIdx.x >> ksbits;
    const int rg   = rest & 1;
    const int tile = rest >> 1;
    const int c0   = tile * NT;
    const int row0 = rg * 64;
    const int kt0  = ks * nkt;

    const int r0 = tid >> 3, kc = tid & 7;
    const float* aP = act + (row0 + r0) * 1024 + kt0 * 64 + kc * 8;
    const float* wP = wgt + (c0 + r0) * 1024 + kt0 * 64 + kc * 8;
    const bool wAct = (tid < NT * 8);

    const int saI0 = (r0 * 64 + kc * 8) ^ ((r0 & 7) << 3);
    const int saI1 = ((r0 + 32) * 64 + kc * 8) ^ ((r0 & 7) << 3);

    f32x4 A[4][4], W[4][2];
    f32x4 acc[CT] = {};

#define ISSUE(kt, s) do {                                                 \
        A[s][0] = *(const f32x4*)(aP + (kt) * 64);                        \
        A[s][1] = *(const f32x4*)(aP + (kt) * 64 + 4);                    \
        A[s][2] = *(const f32x4*)(aP + (kt) * 64 + 32768);                \
        A[s][3] = *(const f32x4*)(aP + (kt) * 64 + 32772);                \
        if (wAct) {                                                       \
            W[s][0] = *(const f32x4*)(wP + (kt) * 64);                    \
            W[s][1] = *(const f32x4*)(wP + (kt) * 64 + 4);                \
        }                                                                 \
    } while (0)

#define RL(v) (RELUA ? fmaxf((v), 0.0f) : (v))

#define STAGE(s, b) do {                                                  \
        int4 p0, p1;                                                      \
        p0.x = cvt2(RL(A[s][0][0]), RL(A[s][0][1]));                      \
        p0.y = cvt2(RL(A[s][0][2]), RL(A[s][0][3]));                      \
        p0.z = cvt2(RL(A[s][1][0]), RL(A[s][1][1]));                      \
        p0.w = cvt2(RL(A[s][1][2]), RL(A[s][1][3]));                      \
        p1.x = cvt2(RL(A[s][2][0]), RL(A[s][2][1]));                      \
        p1.y = cvt2(RL(A[s][2][2]), RL(A[s][2][3]));                      \
        p1.z = cvt2(RL(A[s][3][0]), RL(A[s][3][1]));                      \
        p1.w = cvt2(RL(A[s][3][2]), RL(A[s][3][3]));                      \
        *(int4*)&As[b][saI0] = p0;                                        \
        *(int4*)&As[b][saI1] = p1;                                        \
        if (wAct) {                                                       \
            int4 q;                                                       \
            q.x = cvt2(W[s][0][0], W[s][0][1]);                           \
            q.y = cvt2(W[s][0][2], W[s][0][3]);                           \
            q.z = cvt2(W[s][1][0], W[s][1][1]);                           \
            q.w = cvt2(W[s][1][2], W[s][1][3]);                           \
            *(int4*)&Ws[b][saI0] = q;                                     \
        }                                                                 \
    } while (0)

#define COMPUTE(b) do {                                                   \
        _Pragma("unroll")                                                 \
        for (int kk = 0; kk < 64; kk += 32) {                             \
            const int kw = kk + 8 * (lane >> 4);                          \
            const int ar = wv * 16 + (lane & 15);                         \
            bf16x8 af = *(const bf16x8*)&As[b][(ar * 64 + kw) ^ ((ar & 7) << 3)]; \
            bf16x8 bw[CT];                                                \
            _Pragma("unroll")                                             \
            for (int ct = 0; ct < CT; ++ct) {                             \
                int br = ct * 16 + (lane & 15);                           \
                bw[ct] = *(const bf16x8*)&Ws[b][(br * 64 + kw) ^ ((br & 7) << 3)]; \
            }                                                             \
            _Pragma("unroll")                                             \
            for (int ct = 0; ct < CT; ++ct)                               \
                acc[ct] = __builtin_amdgcn_mfma_f32_16x16x32_bf16(        \
                    af, bw[ct], acc[ct], 0, 0, 0);                        \
        }                                                                 \
    } while (0)

    ISSUE(0, 0); ISSUE(1, 1); ISSUE(2, 2); ISSUE(3, 3);

    #pragma unroll 1
    for (int g = 0; g < nkt / 4; ++g) {
        const int kt = 4 * g;
        STAGE(0, 0); if (kt + 4 < nkt) ISSUE(kt + 4, 0); BAR(); COMPUTE(0);
        STAGE(1, 1); if (kt + 5 < nkt) ISSUE(kt + 5, 1); BAR(); COMPUTE(1);
        STAGE(2, 0); if (kt + 6 < nkt) ISSUE(kt + 6, 2); BAR(); COMPUTE(0);
        STAGE(3, 1); if (kt + 7 < nkt) ISSUE(kt + 7, 3); BAR(); COMPUTE(1);
    }

#undef ISSUE
#undef RL
#undef STAGE
#undef COMPUTE

    #pragma unroll
    for (int ct = 0; ct < CT; ++ct) {
        int col = c0 + ct * 16 + (lane & 15);
        float bv = (bias && ks == 0) ? bias[col] : 0.0f;
        #pragma unroll
        for (int r = 0; r < 4; ++r) {
            int row = row0 + wv * 16 + (lane >> 4) * 4 + r;
            float v = acc[ct][r] + bv;
            if (ATOMIC) unsafeAtomicAdd(&out[row * ldo + col], v);
            else        out[row * ldo + col] = v;
        }
    }
}

extern "C" void kernel_launch(void* const* d_in, const int* in_sizes, int n_in,
                              void* d_out, int out_size, void* d_ws, size_t ws_size,
                              hipStream_t stream)
{
    const float* x     = (const float*)d_in[0];
    const float* h1    = (const float*)d_in[1];
    const float* w_ih  = (const float*)d_in[2];
    const float* w_hh  = (const float*)d_in[3];
    const float* b_ih  = (const float*)d_in[4];
    const float* b_hh  = (const float*)d_in[5];
    const float* w_fc1 = (const float*)d_in[6];
    const float* b_fc1 = (const float*)d_in[7];
    const float* w_fc3 = (const float*)d_in[8];
    const float* b_fc3 = (const float*)d_in[9];

    float* out = (float*)d_out;          // [128][256]
    float* h1p = out + 128 * 256;        // [128][1024]

    float* ws  = (float*)d_ws;
    float* res = ws;                     // [128][1024] h1' + x
    float* f1p = ws + 128 * 1024;        // [128][1024] fc1 pre-activation

    // fused gates GEMM + GRU -> h1p (d_out) and res; zeroes f1p and out
    gates_k<<<128, 256, 0, stream>>>(x, h1, w_ih, w_hh, b_ih, b_hh,
                                     h1p, res, f1p, out);
    // f1p += res @ w_fc1^T + b_fc1   (64 tiles x 2 rg x 2 ksplit = 256 blocks)
    gemm_k<16, true, false><<<256, 256, 0, stream>>>(
        res, w_fc1, b_fc1, f1p, 1024, 8, 1);
    // out += relu(f1p) @ w_fc3^T + b_fc3  (16 x 2 x 2 = 64 blocks)
    gemm_k<16, true, true><<<64, 256, 0, stream>>>(
        f1p, w_fc3, b_fc3, out, 256, 8, 1);
}